// Round 16
// baseline (2451.516 us; speedup 1.0000x reference)
//
#include <hip/hip_runtime.h>
#include <stdint.h>

#define NE    8
#define HID   2048
#define INTER 7168
#define TTOK  8192
#define NT1   (HID / 64)    // 32 K-tiles for pass1
#define NT2   (INTER / 64)  // 112 K-tiles for pass2

typedef __bf16 bf16;
typedef bf16 bf16x4 __attribute__((ext_vector_type(4)));
typedef bf16 bf16x8 __attribute__((ext_vector_type(8)));
typedef float f32x4 __attribute__((ext_vector_type(4)));

__device__ __forceinline__ void glds16(const void* g, void* l) {
  __builtin_amdgcn_global_load_lds((__attribute__((address_space(1))) void*)g,
                                   (__attribute__((address_space(3))) void*)l, 16, 0, 0);
}

// ---------------- fp32 -> bf16 conversion: w1,w3,w2 in ONE launch ----------------
__global__ void cvt3_kernel(const float* __restrict__ s0, const float* __restrict__ s1,
                            const float* __restrict__ s2, bf16* __restrict__ dst) {
  const long SEG = (long)NE * INTER * HID;
  const int seg = blockIdx.x >> 12;
  const int bid = blockIdx.x & 4095;
  const float* src = (seg == 0) ? s0 : ((seg == 1) ? s1 : s2);
  bf16* d = dst + (size_t)seg * SEG;
  long i = (long)bid * blockDim.x + threadIdx.x;
  const long stride = (long)4096 * blockDim.x;
  for (long j = i * 4; j < SEG; j += stride * 4) {
    float4 v = *(const float4*)(src + j);
    bf16x4 o = {(bf16)v.x, (bf16)v.y, (bf16)v.z, (bf16)v.w};
    *(bf16x4*)(d + j) = o;
  }
}

// ---------------- router (also emits bf16 x) ----------------
__global__ void router_kernel(const float* __restrict__ x, const float* __restrict__ gw,
                              bf16* __restrict__ xb,
                              int* __restrict__ topk_e, float* __restrict__ topk_w) {
  const int wid = threadIdx.x >> 6, lane = threadIdx.x & 63;
  const int t = blockIdx.x * 4 + wid;
  if (t >= TTOK) return;
  const float* xr = x + (size_t)t * HID;
  bf16* xw = xb + (size_t)t * HID;
  float xv[32];
#pragma unroll
  for (int i = 0; i < 32; ++i) xv[i] = xr[lane + 64 * i];
#pragma unroll
  for (int i = 0; i < 32; ++i) xw[lane + 64 * i] = (bf16)xv[i];
  float lg[NE];
#pragma unroll
  for (int e = 0; e < NE; ++e) {
    const float* g = gw + e * HID;
    float s = 0.f;
#pragma unroll
    for (int i = 0; i < 32; ++i) s += xv[i] * g[lane + 64 * i];
#pragma unroll
    for (int off = 32; off; off >>= 1) s += __shfl_down(s, off);
    lg[e] = s;
  }
  if (lane == 0) {
    int i1 = 0;
#pragma unroll
    for (int e = 1; e < NE; ++e) if (lg[e] > lg[i1]) i1 = e;
    int i2 = (i1 == 0) ? 1 : 0;
#pragma unroll
    for (int e = 0; e < NE; ++e) if (e != i2 && e != i1 && lg[e] > lg[i2]) i2 = e;
    float r = __expf(lg[i2] - lg[i1]);
    float wa = 1.f / (1.f + r);
    topk_e[2 * t] = i1; topk_e[2 * t + 1] = i2;
    topk_w[2 * t] = wa; topk_w[2 * t + 1] = 1.f - wa;
  }
}

// ---------------- stable sorted gather (wave-scan) + inverse map ----------------
__global__ void gather_sorted(const int* __restrict__ topk_e, const float* __restrict__ topk_w,
                              int* __restrict__ cnt, int* __restrict__ ltok,
                              float* __restrict__ lw, int* __restrict__ ppos) {
  const int e = blockIdx.x;
  const int tid = threadIdx.x;
  const int lane = tid & 63, wv = tid >> 6;
  __shared__ int wtot[4];
  __shared__ int basesh;
  if (tid == 0) basesh = 0;
  __syncthreads();
  for (int c0 = 0; c0 < TTOK; c0 += 256) {
    const int t = c0 + tid;
    const int e0 = topk_e[2 * t], e1 = topk_e[2 * t + 1];
    const int j = (e0 == e) ? 0 : 1;
    const int flag = (e0 == e) || (e1 == e);
    unsigned long long b = __ballot(flag);
    int wrank = __popcll(b & ((1ULL << lane) - 1ULL));
    if (lane == 63) wtot[wv] = __popcll(b);
    __syncthreads();
    int wbase = 0;
#pragma unroll
    for (int k = 0; k < 4; ++k) if (k < wv) wbase += wtot[k];
    const int total = wtot[0] + wtot[1] + wtot[2] + wtot[3];
    const int pos = basesh + wbase + wrank;
    if (flag) {
      ltok[e * TTOK + pos] = t;
      lw[e * TTOK + pos] = (j == 0) ? topk_w[2 * t] : topk_w[2 * t + 1];
      ppos[2 * t + j] = pos;
    }
    __syncthreads();
    if (tid == 0) basesh += total;
    __syncthreads();
  }
  if (tid == 0) cnt[e] = basesh;
}

// ---------------- combine: out[t] = y[pair0(t)] + y[pair1(t)]  (bf16 ybuf) ----------------
__global__ void combine_kernel(const bf16* __restrict__ ybuf, const int* __restrict__ topk_e,
                               const int* __restrict__ ppos, const int* __restrict__ cnt,
                               float* __restrict__ out) {
  __shared__ int pref[NE];
  if (threadIdx.x < NE) {
    int b = 0;
    for (int k = 0; k < (int)threadIdx.x; ++k) b += cnt[k];
    pref[threadIdx.x] = b;
  }
  __syncthreads();
  const int t = blockIdx.x;
  const int col = threadIdx.x * 8;
  const int g0 = pref[topk_e[2 * t]] + ppos[2 * t];
  const int g1 = pref[topk_e[2 * t + 1]] + ppos[2 * t + 1];
  bf16x8 y0 = *(const bf16x8*)(ybuf + (size_t)g0 * HID + col);
  bf16x8 y1 = *(const bf16x8*)(ybuf + (size_t)g1 * HID + col);
  float4 o0, o1;
  o0.x = (float)y0[0] + (float)y1[0]; o0.y = (float)y0[1] + (float)y1[1];
  o0.z = (float)y0[2] + (float)y1[2]; o0.w = (float)y0[3] + (float)y1[3];
  o1.x = (float)y0[4] + (float)y1[4]; o1.y = (float)y0[5] + (float)y1[5];
  o1.z = (float)y0[6] + (float)y1[6]; o1.w = (float)y0[7] + (float)y1[7];
  float4* o = (float4*)(out + (size_t)t * HID + col);
  o[0] = o0; o[1] = o1;
}

// ============ 256x256 GEMM, 16x16x32 MFMA, counted-lgkm (r14) + XCD swizzle ============
// Grid flattened 1D; m204 bijective swizzle l=(d&7)*C+(d>>3) (C=nwg/8 exact) with
// tm-FASTEST decode: consecutive working blocks share one weight panel (1 MB pass1 /
// 3.7 MB pass2, fits per-XCD L2) and each XCD owns one expert's contiguous range.
// A/hbuf rows are served by L3 (32/235 MB). Mechanism: stage-B glds hits L2 instead
// of HBM -> the counted-vmcnt pipeline (~2-slot depth) stops stalling per K-tile.
// Sync skeleton identical to r11/r14 (race-audited; vmcnt(6)@s4, LGKMC 12/8/4/0).

#define MFMA(a, b, c) __builtin_amdgcn_mfma_f32_16x16x32_bf16((a), (b), (c), 0, 0, 0)

#define STAGE_A(h, kt) do { int _b = ((kt) & 1) * 32768; size_t _k = (size_t)(kt) * 128; \
    glds16(bA + oA[(h)*2 + 0] + _k, ldsA + _b + (h) * 16384 + d0); \
    glds16(bA + oA[(h)*2 + 1] + _k, ldsA + _b + (h) * 16384 + d1); } while (0)
#define STAGE_B(h, kt) do { int _b = ((kt) & 1) * 32768; size_t _k = (size_t)(kt) * 128; \
    glds16(bB + oB[(h)*2 + 0] + _k, ldsB + _b + (h) * 16384 + d0); \
    glds16(bB + oB[(h)*2 + 1] + _k, ldsB + _b + (h) * 16384 + d1); } while (0)

#define RD_A(mf, ks) (*(const bf16x8*)(ldsA + curb + arow + (mf) * (16 * 128) + ((ks) ? kcol1 : kcol0)))
#define RD_B(nf, ks) (*(const bf16x8*)(ldsB + curb + brow + (nf) * (16 * 128) + ((ks) ? kcol1 : kcol0)))

#define BAR()    __builtin_amdgcn_s_barrier()
#define LGKMC(n) do { asm volatile("s_waitcnt lgkmcnt(" #n ")" ::: "memory"); \
                      __builtin_amdgcn_sched_barrier(0); } while (0)
#define SCHED0() __builtin_amdgcn_sched_barrier(0)

#define Q_MFMA(AM, BM, ACCM, ACCN_OFF) do { \
  __builtin_amdgcn_s_setprio(1); \
  _Pragma("unroll") \
  for (int m = 0; m < 4; ++m) \
    _Pragma("unroll") \
    for (int n = 0; n < 2; ++n) { \
      acc[ACCM + m][ACCN_OFF + n] = MFMA(AM[m][0], BM[n][0], acc[ACCM + m][ACCN_OFF + n]); \
      acc[ACCM + m][ACCN_OFF + n] = MFMA(AM[m][1], BM[n][1], acc[ACCM + m][ACCN_OFF + n]); \
    } \
  __builtin_amdgcn_s_setprio(0); \
} while (0)

// ---------------- pass1: h = silu(x w1^T) * (x w3^T) ----------------
__launch_bounds__(512, 2)
__global__ void pass1_kernel(const bf16* __restrict__ xb, const bf16* __restrict__ w1b,
                             bf16* __restrict__ hbuf, const int* __restrict__ cnt,
                             const int* __restrict__ ltok) {
  // XCD swizzle: nwg = 32*56*8 = 14336, C = 1792; tm fastest
  const int d = blockIdx.x;
  const int l = (d & 7) * 1792 + (d >> 3);
  const int tm = l & 31;
  const int tn = (l >> 5) % 56;
  const int e = l / 1792;
  const int c = cnt[e];
  if (tm * 256 >= c) return;
  int be = 0;
#pragma unroll
  for (int k = 0; k < NE; ++k) if (k < e) be += cnt[k];

  __shared__ __align__(16) bf16 sA[2][256 * 64];
  __shared__ __align__(16) bf16 sB[2][256 * 64];
  char* const ldsA = (char*)&sA[0][0];
  char* const ldsB = (char*)&sB[0][0];

  const int tid = threadIdx.x;
  const int r0 = tid >> 3;
  const int ls = (tid & 7) ^ (r0 & 7);
  const int d0 = tid * 16, d1 = (tid + 512) * 16;
  const char* const bA = (const char*)xb;
  const char* const bB = (const char*)w1b;  // w3b contiguous after w1b

  uint32_t oA[4], oB[4];
#pragma unroll
  for (int i = 0; i < 4; ++i) {
    int slot = tm * 256 + i * 64 + r0; if (slot >= c) slot = c - 1;
    oA[i] = (uint32_t)((size_t)ltok[e * TTOK + slot] * (HID * 2) + ls * 16);
    int br = i * 64 + r0;
    int w = (br >> 4) & 1;
    int wr = tn * 128 + ((br >> 5) << 4) + (br & 15);
    size_t off = ((size_t)e * INTER + wr) * (HID * 2) + (size_t)ls * 16;
    if (w) off += (size_t)NE * INTER * HID * 2;
    oB[i] = (uint32_t)off;
  }

  const int lane = tid & 63, wid = tid >> 6;
  const int wm = wid >> 2, wn = wid & 3;
  const int ln15 = lane & 15, kq = lane >> 4;
  const int swz = (ln15 & 7) << 4;
  const int kcol0 = (kq * 16) ^ swz;
  const int kcol1 = (64 + kq * 16) ^ swz;
  const int arow = (wm * 128 + ln15) * 128;
  const int brow = (wn * 64 + ln15) * 128;

  f32x4 acc[8][4];
#pragma unroll
  for (int m = 0; m < 8; ++m)
#pragma unroll
    for (int n = 0; n < 4; ++n) acc[m][n] = (f32x4){0.f, 0.f, 0.f, 0.f};

  STAGE_A(0, 0); STAGE_A(1, 0); STAGE_B(0, 0); STAGE_B(1, 0);
  asm volatile("s_waitcnt vmcnt(4)" ::: "memory");
  STAGE_A(0, 1); STAGE_A(1, 1); STAGE_B(0, 1);
  asm volatile("s_waitcnt vmcnt(6)" ::: "memory");
  BAR();

  bf16x8 a0[4][2], a1[4][2], b0[2][2], b1[2][2];
  int cur = 0;
  for (int t = 0; t < NT1; ++t, cur ^= 1) {
    const int curb = cur * 32768;
    // ---- s1: read a0+b0(t); stage B1(t+1); MFMA Q11(t-1) ----
#pragma unroll
    for (int m = 0; m < 4; ++m) { a0[m][0] = RD_A(m, 0); a0[m][1] = RD_A(m, 1); }
#pragma unroll
    for (int n = 0; n < 2; ++n) { b0[n][0] = RD_B(n, 0); b0[n][1] = RD_B(n, 1); }
    if (t + 1 < NT1) STAGE_B(1, t + 1);
    BAR(); LGKMC(12);
    if (t > 0) Q_MFMA(a1, b1, 4, 2);
    BAR();
    // ---- s2: read a1(t); MFMA Q00(t) ----
#pragma unroll
    for (int m = 0; m < 4; ++m) { a1[m][0] = RD_A(4 + m, 0); a1[m][1] = RD_A(4 + m, 1); }
    BAR(); LGKMC(8);
    Q_MFMA(a0, b0, 0, 0);
    BAR();
    // ---- s3: read b1(t); stage A0+A1(t+2); MFMA Q10(t) ----
#pragma unroll
    for (int n = 0; n < 2; ++n) { b1[n][0] = RD_B(2 + n, 0); b1[n][1] = RD_B(2 + n, 1); }
    if (t + 2 < NT1) { STAGE_A(0, t + 2); STAGE_A(1, t + 2); SCHED0(); }
    BAR(); LGKMC(4);
    Q_MFMA(a1, b0, 4, 0);
    BAR();
    // ---- s4: stage B0(t+2); MFMA Q01(t); counted vmcnt ----
    if (t + 2 < NT1) STAGE_B(0, t + 2);
    LGKMC(0);
    Q_MFMA(a0, b1, 0, 2);
    if (t + 2 < NT1) asm volatile("s_waitcnt vmcnt(6)" ::: "memory");
    else             asm volatile("s_waitcnt vmcnt(0)" ::: "memory");
    BAR();
  }
  Q_MFMA(a1, b1, 4, 2);

  // epilogue: silu(g)*u
#pragma unroll
  for (int mh = 0; mh < 2; ++mh)
#pragma unroll
    for (int mf = 0; mf < 4; ++mf)
#pragma unroll
      for (int j = 0; j < 4; ++j) {
        const int slot = tm * 256 + wm * 128 + mh * 64 + mf * 16 + kq * 4 + j;
        if (slot < c) {
          bf16* hrow = hbuf + (size_t)(be + slot) * INTER + tn * 128;
#pragma unroll
          for (int p = 0; p < 2; ++p) {
            const float g = acc[mh * 4 + mf][2 * p][j];
            const float u = acc[mh * 4 + mf][2 * p + 1][j];
            const float hv = g / (1.f + __expf(-g)) * u;
            hrow[wn * 32 + p * 16 + ln15] = (bf16)hv;
          }
        }
      }
}

// ---------------- pass2: ybuf[pair,:] = w * (h w2^T), bf16 out ----------------
__launch_bounds__(512, 2)
__global__ void pass2_kernel(const bf16* __restrict__ hbuf, const bf16* __restrict__ w2b,
                             bf16* __restrict__ ybuf, const int* __restrict__ cnt,
                             const float* __restrict__ lw) {
  // XCD swizzle: nwg = 32*8*8 = 2048, C = 256; tm fastest
  const int d = blockIdx.x;
  const int l = (d & 7) * 256 + (d >> 3);
  const int tm = l & 31;
  const int tn = (l >> 5) & 7;
  const int e = l >> 8;
  const int c = cnt[e];
  if (tm * 256 >= c) return;
  int be = 0;
#pragma unroll
  for (int k = 0; k < NE; ++k) if (k < e) be += cnt[k];

  __shared__ __align__(16) bf16 sA[2][256 * 64];
  __shared__ __align__(16) bf16 sB[2][256 * 64];
  char* const ldsA = (char*)&sA[0][0];
  char* const ldsB = (char*)&sB[0][0];

  const int tid = threadIdx.x;
  const int r0 = tid >> 3;
  const int ls = (tid & 7) ^ (r0 & 7);
  const int d0 = tid * 16, d1 = (tid + 512) * 16;
  const char* const bA = (const char*)hbuf;
  const char* const bB = (const char*)w2b;

  uint32_t oA[4], oB[4];
#pragma unroll
  for (int i = 0; i < 4; ++i) {
    int slot = tm * 256 + i * 64 + r0; if (slot >= c) slot = c - 1;
    oA[i] = (uint32_t)((size_t)(be + slot) * (INTER * 2) + ls * 16);
    oB[i] = (uint32_t)(((size_t)e * HID + tn * 256 + i * 64 + r0) * (INTER * 2) + (size_t)ls * 16);
  }

  const int lane = tid & 63, wid = tid >> 6;
  const int wm = wid >> 2, wn = wid & 3;
  const int ln15 = lane & 15, kq = lane >> 4;
  const int swz = (ln15 & 7) << 4;
  const int kcol0 = (kq * 16) ^ swz;
  const int kcol1 = (64 + kq * 16) ^ swz;
  const int arow = (wm * 128 + ln15) * 128;
  const int brow = (wn * 64 + ln15) * 128;

  f32x4 acc[8][4];
#pragma unroll
  for (int m = 0; m < 8; ++m)
#pragma unroll
    for (int n = 0; n < 4; ++n) acc[m][n] = (f32x4){0.f, 0.f, 0.f, 0.f};

  STAGE_A(0, 0); STAGE_A(1, 0); STAGE_B(0, 0); STAGE_B(1, 0);
  asm volatile("s_waitcnt vmcnt(4)" ::: "memory");
  STAGE_A(0, 1); STAGE_A(1, 1); STAGE_B(0, 1);
  asm volatile("s_waitcnt vmcnt(6)" ::: "memory");
  BAR();

  bf16x8 a0[4][2], a1[4][2], b0[2][2], b1[2][2];
  int cur = 0;
  for (int t = 0; t < NT2; ++t, cur ^= 1) {
    const int curb = cur * 32768;
    // ---- s1 ----
#pragma unroll
    for (int m = 0; m < 4; ++m) { a0[m][0] = RD_A(m, 0); a0[m][1] = RD_A(m, 1); }
#pragma unroll
    for (int n = 0; n < 2; ++n) { b0[n][0] = RD_B(n, 0); b0[n][1] = RD_B(n, 1); }
    if (t + 1 < NT2) STAGE_B(1, t + 1);
    BAR(); LGKMC(12);
    if (t > 0) Q_MFMA(a1, b1, 4, 2);
    BAR();
    // ---- s2 ----
#pragma unroll
    for (int m = 0; m < 4; ++m) { a1[m][0] = RD_A(4 + m, 0); a1[m][1] = RD_A(4 + m, 1); }
    BAR(); LGKMC(8);
    Q_MFMA(a0, b0, 0, 0);
    BAR();
    // ---- s3 ----
#pragma unroll
    for (int n = 0; n < 2; ++n) { b1[n][0] = RD_B(2 + n, 0); b1[n][1] = RD_B(2 + n, 1); }
    if (t + 2 < NT2) { STAGE_A(0, t + 2); STAGE_A(1, t + 2); SCHED0(); }
    BAR(); LGKMC(4);
    Q_MFMA(a1, b0, 4, 0);
    BAR();
    // ---- s4 ----
    if (t + 2 < NT2) STAGE_B(0, t + 2);
    LGKMC(0);
    Q_MFMA(a0, b1, 0, 2);
    if (t + 2 < NT2) asm volatile("s_waitcnt vmcnt(6)" ::: "memory");
    else             asm volatile("s_waitcnt vmcnt(0)" ::: "memory");
    BAR();
  }
  Q_MFMA(a1, b1, 4, 2);

#pragma unroll
  for (int mh = 0; mh < 2; ++mh)
#pragma unroll
    for (int mf = 0; mf < 4; ++mf)
#pragma unroll
      for (int j = 0; j < 4; ++j) {
        const int slot = tm * 256 + wm * 128 + mh * 64 + mf * 16 + kq * 4 + j;
        if (slot < c) {
          const float wt = lw[e * TTOK + slot];
          bf16* yrow = ybuf + (size_t)(be + slot) * HID + tn * 256;
#pragma unroll
          for (int n = 0; n < 4; ++n)
            yrow[wn * 64 + n * 16 + ln15] = (bf16)(wt * acc[mh * 4 + mf][n][j]);
        }
      }
}

extern "C" void kernel_launch(void* const* d_in, const int* in_sizes, int n_in,
                              void* d_out, int out_size, void* d_ws, size_t ws_size,
                              hipStream_t stream) {
  const float* x  = (const float*)d_in[0];
  const float* gw = (const float*)d_in[1];
  const float* w1 = (const float*)d_in[2];
  const float* w3 = (const float*)d_in[3];
  const float* w2 = (const float*)d_in[4];
  float* out = (float*)d_out;

  char* ws = (char*)d_ws;
  size_t off = 0;
  auto take = [&](size_t bytes) -> char* {
    char* p = ws + off;
    off += (bytes + 255) & ~(size_t)255;
    return p;
  };
  bf16* xb    = (bf16*)take((size_t)TTOK * HID * 2);         // 32 MB
  bf16* w1b   = (bf16*)take((size_t)NE * INTER * HID * 2);   // w3b, w2b MUST follow contiguously
  bf16* w3b   = (bf16*)take((size_t)NE * INTER * HID * 2);
  bf16* w2b   = (bf16*)take((size_t)NE * HID * INTER * 2);
  bf16* hbuf  = (bf16*)take((size_t)TTOK * 2 * INTER * 2);   // 235 MB
  bf16* ybuf  = (bf16*)take((size_t)TTOK * 2 * HID * 2);     // 67 MB
  int*   topk_e = (int*)take(TTOK * 2 * 4);
  float* topk_w = (float*)take(TTOK * 2 * 4);
  int*   ltok   = (int*)take(NE * TTOK * 4);
  float* lwgt   = (float*)take(NE * TTOK * 4);
  int*   ppos   = (int*)take(TTOK * 2 * 4);
  int*   cntp   = (int*)take(64);
  if (off > ws_size) return;
  (void)w3b; (void)w2b;

  cvt3_kernel<<<3 * 4096, 256, 0, stream>>>(w1, w3, w2, w1b);

  router_kernel<<<TTOK / 4, 256, 0, stream>>>(x, gw, xb, topk_e, topk_w);
  gather_sorted<<<NE, 256, 0, stream>>>(topk_e, topk_w, cntp, ltok, lwgt, ppos);

  pass1_kernel<<<32 * 56 * NE, 512, 0, stream>>>(xb, w1b, hbuf, cntp, ltok);
  pass2_kernel<<<32 * 8 * NE, 512, 0, stream>>>(hbuf, w2b, ybuf, cntp, lwgt);
  combine_kernel<<<TTOK, 256, 0, stream>>>(ybuf, topk_e, ppos, cntp, out);
}

// Round 17
// 2107.520 us; speedup vs baseline: 1.1632x; 1.1632x over previous
//
#include <hip/hip_runtime.h>
#include <stdint.h>

#define NE    8
#define HID   2048
#define INTER 7168
#define TTOK  8192
#define NT1   (HID / 64)    // 32 K-tiles for pass1
#define NT2   (INTER / 64)  // 112 K-tiles for pass2

typedef __bf16 bf16;
typedef bf16 bf16x4 __attribute__((ext_vector_type(4)));
typedef bf16 bf16x8 __attribute__((ext_vector_type(8)));
typedef float f32x4 __attribute__((ext_vector_type(4)));

__device__ __forceinline__ void glds16(const void* g, void* l) {
  __builtin_amdgcn_global_load_lds((__attribute__((address_space(1))) void*)g,
                                   (__attribute__((address_space(3))) void*)l, 16, 0, 0);
}

// ---------------- fp32 -> bf16 conversion: w1,w3,w2 in ONE launch ----------------
__global__ void cvt3_kernel(const float* __restrict__ s0, const float* __restrict__ s1,
                            const float* __restrict__ s2, bf16* __restrict__ dst) {
  const long SEG = (long)NE * INTER * HID;
  const int seg = blockIdx.x >> 12;
  const int bid = blockIdx.x & 4095;
  const float* src = (seg == 0) ? s0 : ((seg == 1) ? s1 : s2);
  bf16* d = dst + (size_t)seg * SEG;
  long i = (long)bid * blockDim.x + threadIdx.x;
  const long stride = (long)4096 * blockDim.x;
  for (long j = i * 4; j < SEG; j += stride * 4) {
    float4 v = *(const float4*)(src + j);
    bf16x4 o = {(bf16)v.x, (bf16)v.y, (bf16)v.z, (bf16)v.w};
    *(bf16x4*)(d + j) = o;
  }
}

// ---------------- router (also emits bf16 x) ----------------
__global__ void router_kernel(const float* __restrict__ x, const float* __restrict__ gw,
                              bf16* __restrict__ xb,
                              int* __restrict__ topk_e, float* __restrict__ topk_w) {
  const int wid = threadIdx.x >> 6, lane = threadIdx.x & 63;
  const int t = blockIdx.x * 4 + wid;
  if (t >= TTOK) return;
  const float* xr = x + (size_t)t * HID;
  bf16* xw = xb + (size_t)t * HID;
  float xv[32];
#pragma unroll
  for (int i = 0; i < 32; ++i) xv[i] = xr[lane + 64 * i];
#pragma unroll
  for (int i = 0; i < 32; ++i) xw[lane + 64 * i] = (bf16)xv[i];
  float lg[NE];
#pragma unroll
  for (int e = 0; e < NE; ++e) {
    const float* g = gw + e * HID;
    float s = 0.f;
#pragma unroll
    for (int i = 0; i < 32; ++i) s += xv[i] * g[lane + 64 * i];
#pragma unroll
    for (int off = 32; off; off >>= 1) s += __shfl_down(s, off);
    lg[e] = s;
  }
  if (lane == 0) {
    int i1 = 0;
#pragma unroll
    for (int e = 1; e < NE; ++e) if (lg[e] > lg[i1]) i1 = e;
    int i2 = (i1 == 0) ? 1 : 0;
#pragma unroll
    for (int e = 0; e < NE; ++e) if (e != i2 && e != i1 && lg[e] > lg[i2]) i2 = e;
    float r = __expf(lg[i2] - lg[i1]);
    float wa = 1.f / (1.f + r);
    topk_e[2 * t] = i1; topk_e[2 * t + 1] = i2;
    topk_w[2 * t] = wa; topk_w[2 * t + 1] = 1.f - wa;
  }
}

// ---------------- stable sorted gather (wave-scan) + inverse map ----------------
__global__ void gather_sorted(const int* __restrict__ topk_e, const float* __restrict__ topk_w,
                              int* __restrict__ cnt, int* __restrict__ ltok,
                              float* __restrict__ lw, int* __restrict__ ppos) {
  const int e = blockIdx.x;
  const int tid = threadIdx.x;
  const int lane = tid & 63, wv = tid >> 6;
  __shared__ int wtot[4];
  __shared__ int basesh;
  if (tid == 0) basesh = 0;
  __syncthreads();
  for (int c0 = 0; c0 < TTOK; c0 += 256) {
    const int t = c0 + tid;
    const int e0 = topk_e[2 * t], e1 = topk_e[2 * t + 1];
    const int j = (e0 == e) ? 0 : 1;
    const int flag = (e0 == e) || (e1 == e);
    unsigned long long b = __ballot(flag);
    int wrank = __popcll(b & ((1ULL << lane) - 1ULL));
    if (lane == 63) wtot[wv] = __popcll(b);
    __syncthreads();
    int wbase = 0;
#pragma unroll
    for (int k = 0; k < 4; ++k) if (k < wv) wbase += wtot[k];
    const int total = wtot[0] + wtot[1] + wtot[2] + wtot[3];
    const int pos = basesh + wbase + wrank;
    if (flag) {
      ltok[e * TTOK + pos] = t;
      lw[e * TTOK + pos] = (j == 0) ? topk_w[2 * t] : topk_w[2 * t + 1];
      ppos[2 * t + j] = pos;
    }
    __syncthreads();
    if (tid == 0) basesh += total;
    __syncthreads();
  }
  if (tid == 0) cnt[e] = basesh;
}

// ---------------- combine: out[t] = y[pair0(t)] + y[pair1(t)]  (bf16 ybuf) ----------------
__global__ void combine_kernel(const bf16* __restrict__ ybuf, const int* __restrict__ topk_e,
                               const int* __restrict__ ppos, const int* __restrict__ cnt,
                               float* __restrict__ out) {
  __shared__ int pref[NE];
  if (threadIdx.x < NE) {
    int b = 0;
    for (int k = 0; k < (int)threadIdx.x; ++k) b += cnt[k];
    pref[threadIdx.x] = b;
  }
  __syncthreads();
  const int t = blockIdx.x;
  const int col = threadIdx.x * 8;
  const int g0 = pref[topk_e[2 * t]] + ppos[2 * t];
  const int g1 = pref[topk_e[2 * t + 1]] + ppos[2 * t + 1];
  bf16x8 y0 = *(const bf16x8*)(ybuf + (size_t)g0 * HID + col);
  bf16x8 y1 = *(const bf16x8*)(ybuf + (size_t)g1 * HID + col);
  float4 o0, o1;
  o0.x = (float)y0[0] + (float)y1[0]; o0.y = (float)y0[1] + (float)y1[1];
  o0.z = (float)y0[2] + (float)y1[2]; o0.w = (float)y0[3] + (float)y1[3];
  o1.x = (float)y0[4] + (float)y1[4]; o1.y = (float)y0[5] + (float)y1[5];
  o1.z = (float)y0[6] + (float)y1[6]; o1.w = (float)y0[7] + (float)y1[7];
  float4* o = (float4*)(out + (size_t)t * HID + col);
  o[0] = o0; o[1] = o1;
}

// ============ 256x256 GEMM, 16x16x32 MFMA, read-pipelined counted-lgkm (r11/r14) ============
// Best-measured configuration. MFMA runs one slot BEHIND its ds_reads via counted
// lgkmcnt. Swizzle: 16B-slot ^= (row & 7) on glds global source AND ds_read addr.
// Stage slots (race-audited): s1: B1(t+1) [other buf]; s3: A0+A1(t+2) [A readers
// drained at s2 lgkm]; s4: B0(t+2) [B readers drained s3]; vmcnt(6) at s4.

#define MFMA(a, b, c) __builtin_amdgcn_mfma_f32_16x16x32_bf16((a), (b), (c), 0, 0, 0)

#define STAGE_A(h, kt) do { int _b = ((kt) & 1) * 32768; size_t _k = (size_t)(kt) * 128; \
    glds16(bA + oA[(h)*2 + 0] + _k, ldsA + _b + (h) * 16384 + d0); \
    glds16(bA + oA[(h)*2 + 1] + _k, ldsA + _b + (h) * 16384 + d1); } while (0)
#define STAGE_B(h, kt) do { int _b = ((kt) & 1) * 32768; size_t _k = (size_t)(kt) * 128; \
    glds16(bB + oB[(h)*2 + 0] + _k, ldsB + _b + (h) * 16384 + d0); \
    glds16(bB + oB[(h)*2 + 1] + _k, ldsB + _b + (h) * 16384 + d1); } while (0)

#define RD_A(mf, ks) (*(const bf16x8*)(ldsA + curb + arow + (mf) * (16 * 128) + ((ks) ? kcol1 : kcol0)))
#define RD_B(nf, ks) (*(const bf16x8*)(ldsB + curb + brow + (nf) * (16 * 128) + ((ks) ? kcol1 : kcol0)))

#define BAR()    __builtin_amdgcn_s_barrier()
#define LGKMC(n) do { asm volatile("s_waitcnt lgkmcnt(" #n ")" ::: "memory"); \
                      __builtin_amdgcn_sched_barrier(0); } while (0)
#define SCHED0() __builtin_amdgcn_sched_barrier(0)

#define Q_MFMA(AM, BM, ACCM, ACCN_OFF) do { \
  __builtin_amdgcn_s_setprio(1); \
  _Pragma("unroll") \
  for (int m = 0; m < 4; ++m) \
    _Pragma("unroll") \
    for (int n = 0; n < 2; ++n) { \
      acc[ACCM + m][ACCN_OFF + n] = MFMA(AM[m][0], BM[n][0], acc[ACCM + m][ACCN_OFF + n]); \
      acc[ACCM + m][ACCN_OFF + n] = MFMA(AM[m][1], BM[n][1], acc[ACCM + m][ACCN_OFF + n]); \
    } \
  __builtin_amdgcn_s_setprio(0); \
} while (0)

// ---------------- pass1: h = silu(x w1^T) * (x w3^T) ----------------
__launch_bounds__(512, 2)
__global__ void pass1_kernel(const bf16* __restrict__ xb, const bf16* __restrict__ w1b,
                             bf16* __restrict__ hbuf, const int* __restrict__ cnt,
                             const int* __restrict__ ltok) {
  const int e = blockIdx.z;
  const int c = cnt[e];
  const int tm = blockIdx.y;
  if (tm * 256 >= c) return;
  const int tn = blockIdx.x;
  int be = 0;
#pragma unroll
  for (int k = 0; k < NE; ++k) if (k < e) be += cnt[k];

  __shared__ __align__(16) bf16 sA[2][256 * 64];
  __shared__ __align__(16) bf16 sB[2][256 * 64];
  char* const ldsA = (char*)&sA[0][0];
  char* const ldsB = (char*)&sB[0][0];

  const int tid = threadIdx.x;
  const int r0 = tid >> 3;
  const int ls = (tid & 7) ^ (r0 & 7);
  const int d0 = tid * 16, d1 = (tid + 512) * 16;
  const char* const bA = (const char*)xb;
  const char* const bB = (const char*)w1b;  // w3b contiguous after w1b

  uint32_t oA[4], oB[4];
#pragma unroll
  for (int i = 0; i < 4; ++i) {
    int slot = tm * 256 + i * 64 + r0; if (slot >= c) slot = c - 1;
    oA[i] = (uint32_t)((size_t)ltok[e * TTOK + slot] * (HID * 2) + ls * 16);
    int br = i * 64 + r0;
    int w = (br >> 4) & 1;
    int wr = tn * 128 + ((br >> 5) << 4) + (br & 15);
    size_t off = ((size_t)e * INTER + wr) * (HID * 2) + (size_t)ls * 16;
    if (w) off += (size_t)NE * INTER * HID * 2;
    oB[i] = (uint32_t)off;
  }

  const int lane = tid & 63, wid = tid >> 6;
  const int wm = wid >> 2, wn = wid & 3;
  const int ln15 = lane & 15, kq = lane >> 4;
  const int swz = (ln15 & 7) << 4;
  const int kcol0 = (kq * 16) ^ swz;
  const int kcol1 = (64 + kq * 16) ^ swz;
  const int arow = (wm * 128 + ln15) * 128;
  const int brow = (wn * 64 + ln15) * 128;

  f32x4 acc[8][4];
#pragma unroll
  for (int m = 0; m < 8; ++m)
#pragma unroll
    for (int n = 0; n < 4; ++n) acc[m][n] = (f32x4){0.f, 0.f, 0.f, 0.f};

  STAGE_A(0, 0); STAGE_A(1, 0); STAGE_B(0, 0); STAGE_B(1, 0);
  asm volatile("s_waitcnt vmcnt(4)" ::: "memory");
  STAGE_A(0, 1); STAGE_A(1, 1); STAGE_B(0, 1);
  asm volatile("s_waitcnt vmcnt(6)" ::: "memory");
  BAR();

  bf16x8 a0[4][2], a1[4][2], b0[2][2], b1[2][2];
  int cur = 0;
  for (int t = 0; t < NT1; ++t, cur ^= 1) {
    const int curb = cur * 32768;
    // ---- s1: read a0+b0(t); stage B1(t+1); MFMA Q11(t-1) ----
#pragma unroll
    for (int m = 0; m < 4; ++m) { a0[m][0] = RD_A(m, 0); a0[m][1] = RD_A(m, 1); }
#pragma unroll
    for (int n = 0; n < 2; ++n) { b0[n][0] = RD_B(n, 0); b0[n][1] = RD_B(n, 1); }
    if (t + 1 < NT1) STAGE_B(1, t + 1);
    BAR(); LGKMC(12);
    if (t > 0) Q_MFMA(a1, b1, 4, 2);
    BAR();
    // ---- s2: read a1(t); MFMA Q00(t) ----
#pragma unroll
    for (int m = 0; m < 4; ++m) { a1[m][0] = RD_A(4 + m, 0); a1[m][1] = RD_A(4 + m, 1); }
    BAR(); LGKMC(8);
    Q_MFMA(a0, b0, 0, 0);
    BAR();
    // ---- s3: read b1(t); stage A0+A1(t+2); MFMA Q10(t) ----
#pragma unroll
    for (int n = 0; n < 2; ++n) { b1[n][0] = RD_B(2 + n, 0); b1[n][1] = RD_B(2 + n, 1); }
    if (t + 2 < NT1) { STAGE_A(0, t + 2); STAGE_A(1, t + 2); SCHED0(); }
    BAR(); LGKMC(4);
    Q_MFMA(a1, b0, 4, 0);
    BAR();
    // ---- s4: stage B0(t+2); MFMA Q01(t); counted vmcnt ----
    if (t + 2 < NT1) STAGE_B(0, t + 2);
    LGKMC(0);
    Q_MFMA(a0, b1, 0, 2);
    if (t + 2 < NT1) asm volatile("s_waitcnt vmcnt(6)" ::: "memory");
    else             asm volatile("s_waitcnt vmcnt(0)" ::: "memory");
    BAR();
  }
  Q_MFMA(a1, b1, 4, 2);

  // epilogue: silu(g)*u
#pragma unroll
  for (int mh = 0; mh < 2; ++mh)
#pragma unroll
    for (int mf = 0; mf < 4; ++mf)
#pragma unroll
      for (int j = 0; j < 4; ++j) {
        const int slot = tm * 256 + wm * 128 + mh * 64 + mf * 16 + kq * 4 + j;
        if (slot < c) {
          bf16* hrow = hbuf + (size_t)(be + slot) * INTER + tn * 128;
#pragma unroll
          for (int p = 0; p < 2; ++p) {
            const float g = acc[mh * 4 + mf][2 * p][j];
            const float u = acc[mh * 4 + mf][2 * p + 1][j];
            const float hv = g / (1.f + __expf(-g)) * u;
            hrow[wn * 32 + p * 16 + ln15] = (bf16)hv;
          }
        }
      }
}

// ---------------- pass2: ybuf[pair,:] = w * (h w2^T), bf16 out, no atomics ----------------
__launch_bounds__(512, 2)
__global__ void pass2_kernel(const bf16* __restrict__ hbuf, const bf16* __restrict__ w2b,
                             bf16* __restrict__ ybuf, const int* __restrict__ cnt,
                             const float* __restrict__ lw) {
  const int e = blockIdx.z;
  const int c = cnt[e];
  const int tm = blockIdx.y;
  if (tm * 256 >= c) return;
  const int tn = blockIdx.x;
  int be = 0;
#pragma unroll
  for (int k = 0; k < NE; ++k) if (k < e) be += cnt[k];

  __shared__ __align__(16) bf16 sA[2][256 * 64];
  __shared__ __align__(16) bf16 sB[2][256 * 64];
  char* const ldsA = (char*)&sA[0][0];
  char* const ldsB = (char*)&sB[0][0];

  const int tid = threadIdx.x;
  const int r0 = tid >> 3;
  const int ls = (tid & 7) ^ (r0 & 7);
  const int d0 = tid * 16, d1 = (tid + 512) * 16;
  const char* const bA = (const char*)hbuf;
  const char* const bB = (const char*)w2b;

  uint32_t oA[4], oB[4];
#pragma unroll
  for (int i = 0; i < 4; ++i) {
    int slot = tm * 256 + i * 64 + r0; if (slot >= c) slot = c - 1;
    oA[i] = (uint32_t)((size_t)(be + slot) * (INTER * 2) + ls * 16);
    oB[i] = (uint32_t)(((size_t)e * HID + tn * 256 + i * 64 + r0) * (INTER * 2) + (size_t)ls * 16);
  }

  const int lane = tid & 63, wid = tid >> 6;
  const int wm = wid >> 2, wn = wid & 3;
  const int ln15 = lane & 15, kq = lane >> 4;
  const int swz = (ln15 & 7) << 4;
  const int kcol0 = (kq * 16) ^ swz;
  const int kcol1 = (64 + kq * 16) ^ swz;
  const int arow = (wm * 128 + ln15) * 128;
  const int brow = (wn * 64 + ln15) * 128;

  f32x4 acc[8][4];
#pragma unroll
  for (int m = 0; m < 8; ++m)
#pragma unroll
    for (int n = 0; n < 4; ++n) acc[m][n] = (f32x4){0.f, 0.f, 0.f, 0.f};

  STAGE_A(0, 0); STAGE_A(1, 0); STAGE_B(0, 0); STAGE_B(1, 0);
  asm volatile("s_waitcnt vmcnt(4)" ::: "memory");
  STAGE_A(0, 1); STAGE_A(1, 1); STAGE_B(0, 1);
  asm volatile("s_waitcnt vmcnt(6)" ::: "memory");
  BAR();

  bf16x8 a0[4][2], a1[4][2], b0[2][2], b1[2][2];
  int cur = 0;
  for (int t = 0; t < NT2; ++t, cur ^= 1) {
    const int curb = cur * 32768;
    // ---- s1 ----
#pragma unroll
    for (int m = 0; m < 4; ++m) { a0[m][0] = RD_A(m, 0); a0[m][1] = RD_A(m, 1); }
#pragma unroll
    for (int n = 0; n < 2; ++n) { b0[n][0] = RD_B(n, 0); b0[n][1] = RD_B(n, 1); }
    if (t + 1 < NT2) STAGE_B(1, t + 1);
    BAR(); LGKMC(12);
    if (t > 0) Q_MFMA(a1, b1, 4, 2);
    BAR();
    // ---- s2 ----
#pragma unroll
    for (int m = 0; m < 4; ++m) { a1[m][0] = RD_A(4 + m, 0); a1[m][1] = RD_A(4 + m, 1); }
    BAR(); LGKMC(8);
    Q_MFMA(a0, b0, 0, 0);
    BAR();
    // ---- s3 ----
#pragma unroll
    for (int n = 0; n < 2; ++n) { b1[n][0] = RD_B(2 + n, 0); b1[n][1] = RD_B(2 + n, 1); }
    if (t + 2 < NT2) { STAGE_A(0, t + 2); STAGE_A(1, t + 2); SCHED0(); }
    BAR(); LGKMC(4);
    Q_MFMA(a1, b0, 4, 0);
    BAR();
    // ---- s4 ----
    if (t + 2 < NT2) STAGE_B(0, t + 2);
    LGKMC(0);
    Q_MFMA(a0, b1, 0, 2);
    if (t + 2 < NT2) asm volatile("s_waitcnt vmcnt(6)" ::: "memory");
    else             asm volatile("s_waitcnt vmcnt(0)" ::: "memory");
    BAR();
  }
  Q_MFMA(a1, b1, 4, 2);

#pragma unroll
  for (int mh = 0; mh < 2; ++mh)
#pragma unroll
    for (int mf = 0; mf < 4; ++mf)
#pragma unroll
      for (int j = 0; j < 4; ++j) {
        const int slot = tm * 256 + wm * 128 + mh * 64 + mf * 16 + kq * 4 + j;
        if (slot < c) {
          const float wt = lw[e * TTOK + slot];
          bf16* yrow = ybuf + (size_t)(be + slot) * HID + tn * 256;
#pragma unroll
          for (int n = 0; n < 4; ++n)
            yrow[wn * 64 + n * 16 + ln15] = (bf16)(wt * acc[mh * 4 + mf][n][j]);
        }
      }
}

extern "C" void kernel_launch(void* const* d_in, const int* in_sizes, int n_in,
                              void* d_out, int out_size, void* d_ws, size_t ws_size,
                              hipStream_t stream) {
  const float* x  = (const float*)d_in[0];
  const float* gw = (const float*)d_in[1];
  const float* w1 = (const float*)d_in[2];
  const float* w3 = (const float*)d_in[3];
  const float* w2 = (const float*)d_in[4];
  float* out = (float*)d_out;

  char* ws = (char*)d_ws;
  size_t off = 0;
  auto take = [&](size_t bytes) -> char* {
    char* p = ws + off;
    off += (bytes + 255) & ~(size_t)255;
    return p;
  };
  bf16* xb    = (bf16*)take((size_t)TTOK * HID * 2);         // 32 MB
  bf16* w1b   = (bf16*)take((size_t)NE * INTER * HID * 2);   // w3b, w2b MUST follow contiguously
  bf16* w3b   = (bf16*)take((size_t)NE * INTER * HID * 2);
  bf16* w2b   = (bf16*)take((size_t)NE * HID * INTER * 2);
  bf16* hbuf  = (bf16*)take((size_t)TTOK * 2 * INTER * 2);   // 235 MB
  bf16* ybuf  = (bf16*)take((size_t)TTOK * 2 * HID * 2);     // 67 MB
  int*   topk_e = (int*)take(TTOK * 2 * 4);
  float* topk_w = (float*)take(TTOK * 2 * 4);
  int*   ltok   = (int*)take(NE * TTOK * 4);
  float* lwgt   = (float*)take(NE * TTOK * 4);
  int*   ppos   = (int*)take(TTOK * 2 * 4);
  int*   cntp   = (int*)take(64);
  if (off > ws_size) return;
  (void)w3b; (void)w2b;

  cvt3_kernel<<<3 * 4096, 256, 0, stream>>>(w1, w3, w2, w1b);

  router_kernel<<<TTOK / 4, 256, 0, stream>>>(x, gw, xb, topk_e, topk_w);
  gather_sorted<<<NE, 256, 0, stream>>>(topk_e, topk_w, cntp, ltok, lwgt, ppos);

  pass1_kernel<<<dim3(INTER / 128, TTOK / 256, NE), 512, 0, stream>>>(
      xb, w1b, hbuf, cntp, ltok);
  pass2_kernel<<<dim3(HID / 256, TTOK / 256, NE), 512, 0, stream>>>(
      hbuf, w2b, ybuf, cntp, lwgt);
  combine_kernel<<<TTOK, 256, 0, stream>>>(ybuf, topk_e, ppos, cntp, out);
}

// Round 18
// 2104.737 us; speedup vs baseline: 1.1648x; 1.0013x over previous
//
#include <hip/hip_runtime.h>
#include <stdint.h>

#define NE    8
#define HID   2048
#define INTER 7168
#define TTOK  8192
#define NT1   (HID / 64)    // 32 K-tiles for pass1
#define NT2   (INTER / 64)  // 112 K-tiles for pass2

typedef __bf16 bf16;
typedef bf16 bf16x4 __attribute__((ext_vector_type(4)));
typedef bf16 bf16x8 __attribute__((ext_vector_type(8)));
typedef float f32x4 __attribute__((ext_vector_type(4)));

__device__ __forceinline__ void glds16(const void* g, void* l) {
  __builtin_amdgcn_global_load_lds((__attribute__((address_space(1))) void*)g,
                                   (__attribute__((address_space(3))) void*)l, 16, 0, 0);
}

// ---------------- fused: w1/w3 fp32->bf16 cvt + router (+ bf16 x) ----------------
// blocks [0,8192): convert w1 (seg 0) and w3 (seg 1) into w1b|w3b.
// blocks [8192,10240): router over 4 tokens/block (also writes xb).
__global__ void cvtrt_kernel(const float* __restrict__ w1, const float* __restrict__ w3,
                             bf16* __restrict__ wdst,
                             const float* __restrict__ x, const float* __restrict__ gw,
                             bf16* __restrict__ xb,
                             int* __restrict__ topk_e, float* __restrict__ topk_w) {
  const long SEG = (long)NE * INTER * HID;
  if (blockIdx.x < 8192) {
    const int seg = blockIdx.x >> 12;
    const int bid = blockIdx.x & 4095;
    const float* src = seg ? w3 : w1;
    bf16* d = wdst + (size_t)seg * SEG;
    long i = (long)bid * blockDim.x + threadIdx.x;
    const long stride = (long)4096 * blockDim.x;
    for (long j = i * 4; j < SEG; j += stride * 4) {
      float4 v = *(const float4*)(src + j);
      bf16x4 o = {(bf16)v.x, (bf16)v.y, (bf16)v.z, (bf16)v.w};
      *(bf16x4*)(d + j) = o;
    }
    return;
  }
  const int rb = blockIdx.x - 8192;
  const int wid = threadIdx.x >> 6, lane = threadIdx.x & 63;
  const int t = rb * 4 + wid;
  if (t >= TTOK) return;
  const float* xr = x + (size_t)t * HID;
  bf16* xw = xb + (size_t)t * HID;
  float xv[32];
#pragma unroll
  for (int i = 0; i < 32; ++i) xv[i] = xr[lane + 64 * i];
#pragma unroll
  for (int i = 0; i < 32; ++i) xw[lane + 64 * i] = (bf16)xv[i];
  float lg[NE];
#pragma unroll
  for (int e = 0; e < NE; ++e) {
    const float* g = gw + e * HID;
    float s = 0.f;
#pragma unroll
    for (int i = 0; i < 32; ++i) s += xv[i] * g[lane + 64 * i];
#pragma unroll
    for (int off = 32; off; off >>= 1) s += __shfl_down(s, off);
    lg[e] = s;
  }
  if (lane == 0) {
    int i1 = 0;
#pragma unroll
    for (int e = 1; e < NE; ++e) if (lg[e] > lg[i1]) i1 = e;
    int i2 = (i1 == 0) ? 1 : 0;
#pragma unroll
    for (int e = 0; e < NE; ++e) if (e != i2 && e != i1 && lg[e] > lg[i2]) i2 = e;
    float r = __expf(lg[i2] - lg[i1]);
    float wa = 1.f / (1.f + r);
    topk_e[2 * t] = i1; topk_e[2 * t + 1] = i2;
    topk_w[2 * t] = wa; topk_w[2 * t + 1] = 1.f - wa;
  }
}

// ---------------- stable sorted gather (wave-scan) + inverse map ----------------
__global__ void gather_sorted(const int* __restrict__ topk_e, const float* __restrict__ topk_w,
                              int* __restrict__ cnt, int* __restrict__ ltok,
                              float* __restrict__ lw, int* __restrict__ ppos) {
  const int e = blockIdx.x;
  const int tid = threadIdx.x;
  const int lane = tid & 63, wv = tid >> 6;
  __shared__ int wtot[4];
  __shared__ int basesh;
  if (tid == 0) basesh = 0;
  __syncthreads();
  for (int c0 = 0; c0 < TTOK; c0 += 256) {
    const int t = c0 + tid;
    const int e0 = topk_e[2 * t], e1 = topk_e[2 * t + 1];
    const int j = (e0 == e) ? 0 : 1;
    const int flag = (e0 == e) || (e1 == e);
    unsigned long long b = __ballot(flag);
    int wrank = __popcll(b & ((1ULL << lane) - 1ULL));
    if (lane == 63) wtot[wv] = __popcll(b);
    __syncthreads();
    int wbase = 0;
#pragma unroll
    for (int k = 0; k < 4; ++k) if (k < wv) wbase += wtot[k];
    const int total = wtot[0] + wtot[1] + wtot[2] + wtot[3];
    const int pos = basesh + wbase + wrank;
    if (flag) {
      ltok[e * TTOK + pos] = t;
      lw[e * TTOK + pos] = (j == 0) ? topk_w[2 * t] : topk_w[2 * t + 1];
      ppos[2 * t + j] = pos;
    }
    __syncthreads();
    if (tid == 0) basesh += total;
    __syncthreads();
  }
  if (tid == 0) cnt[e] = basesh;
}

// ---------------- combine: out[t] = y[pair0(t)] + y[pair1(t)]  (bf16 ybuf) ----------------
__global__ void combine_kernel(const bf16* __restrict__ ybuf, const int* __restrict__ topk_e,
                               const int* __restrict__ ppos, const int* __restrict__ cnt,
                               float* __restrict__ out) {
  __shared__ int pref[NE];
  if (threadIdx.x < NE) {
    int b = 0;
    for (int k = 0; k < (int)threadIdx.x; ++k) b += cnt[k];
    pref[threadIdx.x] = b;
  }
  __syncthreads();
  const int t = blockIdx.x;
  const int col = threadIdx.x * 8;
  const int g0 = pref[topk_e[2 * t]] + ppos[2 * t];
  const int g1 = pref[topk_e[2 * t + 1]] + ppos[2 * t + 1];
  bf16x8 y0 = *(const bf16x8*)(ybuf + (size_t)g0 * HID + col);
  bf16x8 y1 = *(const bf16x8*)(ybuf + (size_t)g1 * HID + col);
  float4 o0, o1;
  o0.x = (float)y0[0] + (float)y1[0]; o0.y = (float)y0[1] + (float)y1[1];
  o0.z = (float)y0[2] + (float)y1[2]; o0.w = (float)y0[3] + (float)y1[3];
  o1.x = (float)y0[4] + (float)y1[4]; o1.y = (float)y0[5] + (float)y1[5];
  o1.z = (float)y0[6] + (float)y1[6]; o1.w = (float)y0[7] + (float)y1[7];
  float4* o = (float4*)(out + (size_t)t * HID + col);
  o[0] = o0; o[1] = o1;
}

// ============ 256x256 GEMM, 16x16x32 MFMA, read-pipelined counted-lgkm ============
// Best-measured configuration (r11/r14/r17). pass1 carries a LAST z-slice (z==NE,
// dispatched after all GEMM blocks) that converts w2 fp32->bf16 — backfills CUs as
// GEMM blocks retire; kernel boundary guarantees w2b before pass2.

#define MFMA(a, b, c) __builtin_amdgcn_mfma_f32_16x16x32_bf16((a), (b), (c), 0, 0, 0)

#define STAGE_A(h, kt) do { int _b = ((kt) & 1) * 32768; size_t _k = (size_t)(kt) * 128; \
    glds16(bA + oA[(h)*2 + 0] + _k, ldsA + _b + (h) * 16384 + d0); \
    glds16(bA + oA[(h)*2 + 1] + _k, ldsA + _b + (h) * 16384 + d1); } while (0)
#define STAGE_B(h, kt) do { int _b = ((kt) & 1) * 32768; size_t _k = (size_t)(kt) * 128; \
    glds16(bB + oB[(h)*2 + 0] + _k, ldsB + _b + (h) * 16384 + d0); \
    glds16(bB + oB[(h)*2 + 1] + _k, ldsB + _b + (h) * 16384 + d1); } while (0)

#define RD_A(mf, ks) (*(const bf16x8*)(ldsA + curb + arow + (mf) * (16 * 128) + ((ks) ? kcol1 : kcol0)))
#define RD_B(nf, ks) (*(const bf16x8*)(ldsB + curb + brow + (nf) * (16 * 128) + ((ks) ? kcol1 : kcol0)))

#define BAR()    __builtin_amdgcn_s_barrier()
#define LGKMC(n) do { asm volatile("s_waitcnt lgkmcnt(" #n ")" ::: "memory"); \
                      __builtin_amdgcn_sched_barrier(0); } while (0)
#define SCHED0() __builtin_amdgcn_sched_barrier(0)

#define Q_MFMA(AM, BM, ACCM, ACCN_OFF) do { \
  __builtin_amdgcn_s_setprio(1); \
  _Pragma("unroll") \
  for (int m = 0; m < 4; ++m) \
    _Pragma("unroll") \
    for (int n = 0; n < 2; ++n) { \
      acc[ACCM + m][ACCN_OFF + n] = MFMA(AM[m][0], BM[n][0], acc[ACCM + m][ACCN_OFF + n]); \
      acc[ACCM + m][ACCN_OFF + n] = MFMA(AM[m][1], BM[n][1], acc[ACCM + m][ACCN_OFF + n]); \
    } \
  __builtin_amdgcn_s_setprio(0); \
} while (0)

// ---------------- pass1: h = silu(x w1^T) * (x w3^T)  (+ z==NE w2-cvt tail role) ----------------
__launch_bounds__(512, 2)
__global__ void pass1_kernel(const bf16* __restrict__ xb, const bf16* __restrict__ w1b,
                             const float* __restrict__ w2f, bf16* __restrict__ w2b,
                             bf16* __restrict__ hbuf, const int* __restrict__ cnt,
                             const int* __restrict__ ltok) {
  if (blockIdx.z == NE) {
    // w2 fp32 -> bf16 over the LAST z-slice (dispatched after all GEMM blocks)
    const long n4 = (long)NE * HID * INTER / 4;
    long i = (long)(blockIdx.y * gridDim.x + blockIdx.x) * blockDim.x + threadIdx.x;
    const long stride = (long)gridDim.x * gridDim.y * blockDim.x;
    const float4* src = (const float4*)w2f;
    bf16x4* dst = (bf16x4*)w2b;
    for (long j = i; j < n4; j += stride) {
      float4 v = src[j];
      bf16x4 o = {(bf16)v.x, (bf16)v.y, (bf16)v.z, (bf16)v.w};
      dst[j] = o;
    }
    return;
  }
  const int e = blockIdx.z;
  const int c = cnt[e];
  const int tm = blockIdx.y;
  if (tm * 256 >= c) return;
  const int tn = blockIdx.x;
  int be = 0;
#pragma unroll
  for (int k = 0; k < NE; ++k) if (k < e) be += cnt[k];

  __shared__ __align__(16) bf16 sA[2][256 * 64];
  __shared__ __align__(16) bf16 sB[2][256 * 64];
  char* const ldsA = (char*)&sA[0][0];
  char* const ldsB = (char*)&sB[0][0];

  const int tid = threadIdx.x;
  const int r0 = tid >> 3;
  const int ls = (tid & 7) ^ (r0 & 7);
  const int d0 = tid * 16, d1 = (tid + 512) * 16;
  const char* const bA = (const char*)xb;
  const char* const bB = (const char*)w1b;  // w3b contiguous after w1b

  uint32_t oA[4], oB[4];
#pragma unroll
  for (int i = 0; i < 4; ++i) {
    int slot = tm * 256 + i * 64 + r0; if (slot >= c) slot = c - 1;
    oA[i] = (uint32_t)((size_t)ltok[e * TTOK + slot] * (HID * 2) + ls * 16);
    int br = i * 64 + r0;
    int w = (br >> 4) & 1;
    int wr = tn * 128 + ((br >> 5) << 4) + (br & 15);
    size_t off = ((size_t)e * INTER + wr) * (HID * 2) + (size_t)ls * 16;
    if (w) off += (size_t)NE * INTER * HID * 2;
    oB[i] = (uint32_t)off;
  }

  const int lane = tid & 63, wid = tid >> 6;
  const int wm = wid >> 2, wn = wid & 3;
  const int ln15 = lane & 15, kq = lane >> 4;
  const int swz = (ln15 & 7) << 4;
  const int kcol0 = (kq * 16) ^ swz;
  const int kcol1 = (64 + kq * 16) ^ swz;
  const int arow = (wm * 128 + ln15) * 128;
  const int brow = (wn * 64 + ln15) * 128;

  f32x4 acc[8][4];
#pragma unroll
  for (int m = 0; m < 8; ++m)
#pragma unroll
    for (int n = 0; n < 4; ++n) acc[m][n] = (f32x4){0.f, 0.f, 0.f, 0.f};

  STAGE_A(0, 0); STAGE_A(1, 0); STAGE_B(0, 0); STAGE_B(1, 0);
  asm volatile("s_waitcnt vmcnt(4)" ::: "memory");
  STAGE_A(0, 1); STAGE_A(1, 1); STAGE_B(0, 1);
  asm volatile("s_waitcnt vmcnt(6)" ::: "memory");
  BAR();

  bf16x8 a0[4][2], a1[4][2], b0[2][2], b1[2][2];
  int cur = 0;
  for (int t = 0; t < NT1; ++t, cur ^= 1) {
    const int curb = cur * 32768;
    // ---- s1: read a0+b0(t); stage B1(t+1); MFMA Q11(t-1) ----
#pragma unroll
    for (int m = 0; m < 4; ++m) { a0[m][0] = RD_A(m, 0); a0[m][1] = RD_A(m, 1); }
#pragma unroll
    for (int n = 0; n < 2; ++n) { b0[n][0] = RD_B(n, 0); b0[n][1] = RD_B(n, 1); }
    if (t + 1 < NT1) STAGE_B(1, t + 1);
    BAR(); LGKMC(12);
    if (t > 0) Q_MFMA(a1, b1, 4, 2);
    BAR();
    // ---- s2: read a1(t); MFMA Q00(t) ----
#pragma unroll
    for (int m = 0; m < 4; ++m) { a1[m][0] = RD_A(4 + m, 0); a1[m][1] = RD_A(4 + m, 1); }
    BAR(); LGKMC(8);
    Q_MFMA(a0, b0, 0, 0);
    BAR();
    // ---- s3: read b1(t); stage A0+A1(t+2); MFMA Q10(t) ----
#pragma unroll
    for (int n = 0; n < 2; ++n) { b1[n][0] = RD_B(2 + n, 0); b1[n][1] = RD_B(2 + n, 1); }
    if (t + 2 < NT1) { STAGE_A(0, t + 2); STAGE_A(1, t + 2); SCHED0(); }
    BAR(); LGKMC(4);
    Q_MFMA(a1, b0, 4, 0);
    BAR();
    // ---- s4: stage B0(t+2); MFMA Q01(t); counted vmcnt ----
    if (t + 2 < NT1) STAGE_B(0, t + 2);
    LGKMC(0);
    Q_MFMA(a0, b1, 0, 2);
    if (t + 2 < NT1) asm volatile("s_waitcnt vmcnt(6)" ::: "memory");
    else             asm volatile("s_waitcnt vmcnt(0)" ::: "memory");
    BAR();
  }
  Q_MFMA(a1, b1, 4, 2);

  // epilogue: silu(g)*u
#pragma unroll
  for (int mh = 0; mh < 2; ++mh)
#pragma unroll
    for (int mf = 0; mf < 4; ++mf)
#pragma unroll
      for (int j = 0; j < 4; ++j) {
        const int slot = tm * 256 + wm * 128 + mh * 64 + mf * 16 + kq * 4 + j;
        if (slot < c) {
          bf16* hrow = hbuf + (size_t)(be + slot) * INTER + tn * 128;
#pragma unroll
          for (int p = 0; p < 2; ++p) {
            const float g = acc[mh * 4 + mf][2 * p][j];
            const float u = acc[mh * 4 + mf][2 * p + 1][j];
            const float hv = g / (1.f + __expf(-g)) * u;
            hrow[wn * 32 + p * 16 + ln15] = (bf16)hv;
          }
        }
      }
}

// ---------------- pass2: ybuf[pair,:] = w * (h w2^T), bf16 out, no atomics ----------------
__launch_bounds__(512, 2)
__global__ void pass2_kernel(const bf16* __restrict__ hbuf, const bf16* __restrict__ w2b,
                             bf16* __restrict__ ybuf, const int* __restrict__ cnt,
                             const float* __restrict__ lw) {
  const int e = blockIdx.z;
  const int c = cnt[e];
  const int tm = blockIdx.y;
  if (tm * 256 >= c) return;
  const int tn = blockIdx.x;
  int be = 0;
#pragma unroll
  for (int k = 0; k < NE; ++k) if (k < e) be += cnt[k];

  __shared__ __align__(16) bf16 sA[2][256 * 64];
  __shared__ __align__(16) bf16 sB[2][256 * 64];
  char* const ldsA = (char*)&sA[0][0];
  char* const ldsB = (char*)&sB[0][0];

  const int tid = threadIdx.x;
  const int r0 = tid >> 3;
  const int ls = (tid & 7) ^ (r0 & 7);
  const int d0 = tid * 16, d1 = (tid + 512) * 16;
  const char* const bA = (const char*)hbuf;
  const char* const bB = (const char*)w2b;

  uint32_t oA[4], oB[4];
#pragma unroll
  for (int i = 0; i < 4; ++i) {
    int slot = tm * 256 + i * 64 + r0; if (slot >= c) slot = c - 1;
    oA[i] = (uint32_t)((size_t)(be + slot) * (INTER * 2) + ls * 16);
    oB[i] = (uint32_t)(((size_t)e * HID + tn * 256 + i * 64 + r0) * (INTER * 2) + (size_t)ls * 16);
  }

  const int lane = tid & 63, wid = tid >> 6;
  const int wm = wid >> 2, wn = wid & 3;
  const int ln15 = lane & 15, kq = lane >> 4;
  const int swz = (ln15 & 7) << 4;
  const int kcol0 = (kq * 16) ^ swz;
  const int kcol1 = (64 + kq * 16) ^ swz;
  const int arow = (wm * 128 + ln15) * 128;
  const int brow = (wn * 64 + ln15) * 128;

  f32x4 acc[8][4];
#pragma unroll
  for (int m = 0; m < 8; ++m)
#pragma unroll
    for (int n = 0; n < 4; ++n) acc[m][n] = (f32x4){0.f, 0.f, 0.f, 0.f};

  STAGE_A(0, 0); STAGE_A(1, 0); STAGE_B(0, 0); STAGE_B(1, 0);
  asm volatile("s_waitcnt vmcnt(4)" ::: "memory");
  STAGE_A(0, 1); STAGE_A(1, 1); STAGE_B(0, 1);
  asm volatile("s_waitcnt vmcnt(6)" ::: "memory");
  BAR();

  bf16x8 a0[4][2], a1[4][2], b0[2][2], b1[2][2];
  int cur = 0;
  for (int t = 0; t < NT2; ++t, cur ^= 1) {
    const int curb = cur * 32768;
    // ---- s1 ----
#pragma unroll
    for (int m = 0; m < 4; ++m) { a0[m][0] = RD_A(m, 0); a0[m][1] = RD_A(m, 1); }
#pragma unroll
    for (int n = 0; n < 2; ++n) { b0[n][0] = RD_B(n, 0); b0[n][1] = RD_B(n, 1); }
    if (t + 1 < NT2) STAGE_B(1, t + 1);
    BAR(); LGKMC(12);
    if (t > 0) Q_MFMA(a1, b1, 4, 2);
    BAR();
    // ---- s2 ----
#pragma unroll
    for (int m = 0; m < 4; ++m) { a1[m][0] = RD_A(4 + m, 0); a1[m][1] = RD_A(4 + m, 1); }
    BAR(); LGKMC(8);
    Q_MFMA(a0, b0, 0, 0);
    BAR();
    // ---- s3 ----
#pragma unroll
    for (int n = 0; n < 2; ++n) { b1[n][0] = RD_B(2 + n, 0); b1[n][1] = RD_B(2 + n, 1); }
    if (t + 2 < NT2) { STAGE_A(0, t + 2); STAGE_A(1, t + 2); SCHED0(); }
    BAR(); LGKMC(4);
    Q_MFMA(a1, b0, 4, 0);
    BAR();
    // ---- s4 ----
    if (t + 2 < NT2) STAGE_B(0, t + 2);
    LGKMC(0);
    Q_MFMA(a0, b1, 0, 2);
    if (t + 2 < NT2) asm volatile("s_waitcnt vmcnt(6)" ::: "memory");
    else             asm volatile("s_waitcnt vmcnt(0)" ::: "memory");
    BAR();
  }
  Q_MFMA(a1, b1, 4, 2);

#pragma unroll
  for (int mh = 0; mh < 2; ++mh)
#pragma unroll
    for (int mf = 0; mf < 4; ++mf)
#pragma unroll
      for (int j = 0; j < 4; ++j) {
        const int slot = tm * 256 + wm * 128 + mh * 64 + mf * 16 + kq * 4 + j;
        if (slot < c) {
          const float wt = lw[e * TTOK + slot];
          bf16* yrow = ybuf + (size_t)(be + slot) * HID + tn * 256;
#pragma unroll
          for (int n = 0; n < 4; ++n)
            yrow[wn * 64 + n * 16 + ln15] = (bf16)(wt * acc[mh * 4 + mf][n][j]);
        }
      }
}

extern "C" void kernel_launch(void* const* d_in, const int* in_sizes, int n_in,
                              void* d_out, int out_size, void* d_ws, size_t ws_size,
                              hipStream_t stream) {
  const float* x  = (const float*)d_in[0];
  const float* gw = (const float*)d_in[1];
  const float* w1 = (const float*)d_in[2];
  const float* w3 = (const float*)d_in[3];
  const float* w2 = (const float*)d_in[4];
  float* out = (float*)d_out;

  char* ws = (char*)d_ws;
  size_t off = 0;
  auto take = [&](size_t bytes) -> char* {
    char* p = ws + off;
    off += (bytes + 255) & ~(size_t)255;
    return p;
  };
  bf16* xb    = (bf16*)take((size_t)TTOK * HID * 2);         // 32 MB
  bf16* w1b   = (bf16*)take((size_t)NE * INTER * HID * 2);   // w3b MUST follow contiguously
  bf16* w3b   = (bf16*)take((size_t)NE * INTER * HID * 2);
  bf16* w2b   = (bf16*)take((size_t)NE * HID * INTER * 2);
  bf16* hbuf  = (bf16*)take((size_t)TTOK * 2 * INTER * 2);   // 235 MB
  bf16* ybuf  = (bf16*)take((size_t)TTOK * 2 * HID * 2);     // 67 MB
  int*   topk_e = (int*)take(TTOK * 2 * 4);
  float* topk_w = (float*)take(TTOK * 2 * 4);
  int*   ltok   = (int*)take(NE * TTOK * 4);
  float* lwgt   = (float*)take(NE * TTOK * 4);
  int*   ppos   = (int*)take(TTOK * 2 * 4);
  int*   cntp   = (int*)take(64);
  if (off > ws_size) return;
  (void)w3b;

  cvtrt_kernel<<<8192 + TTOK / 4, 256, 0, stream>>>(w1, w3, w1b, x, gw, xb, topk_e, topk_w);
  gather_sorted<<<NE, 256, 0, stream>>>(topk_e, topk_w, cntp, ltok, lwgt, ppos);

  pass1_kernel<<<dim3(INTER / 128, TTOK / 256, NE + 1), 512, 0, stream>>>(
      xb, w1b, w2, w2b, hbuf, cntp, ltok);
  pass2_kernel<<<dim3(HID / 256, TTOK / 256, NE), 512, 0, stream>>>(
      hbuf, w2b, ybuf, cntp, lwgt);
  combine_kernel<<<TTOK, 256, 0, stream>>>(ybuf, topk_e, ppos, cntp, out);
}